// Round 3
// baseline (167.095 us; speedup 1.0000x reference)
//
#include <hip/hip_runtime.h>
#include <math.h>

#define NBATCH 64
#define NANCH_PER 3
#define NCLS 13
#define NH 76
#define NW 76
#define NPIX (NH*NW)             // 5776
#define NG4 (NPIX/4)             // 1444 float4 groups per plane
#define MAXT 50
#define NLC 12
#define NCH (NLC + NCLS)         // 25 channels
#define BETA_C 0.028f
#define EPS_C 1e-12f
#define NET_WH 608.0f
#define SUBB 3                   // sub-blocks per (b,a); each handles 2 chunks of 256 groups
#define NBLK (NBATCH*NANCH_PER*SUBB)  // 576
#define LOGEPS 27.6310211159285f // -log(1e-12)

struct TRec {
  float x1, x2, y1, y2;
  float area;
  int   flat;                   // within-batch flat index (a*NPIX + pix), -1 if invalid
  float iou;                    // iou_t
  int   cls;
  float vals[11];               // tcoord values
  float pad;
};  // 80 B

__device__ __forceinline__ float sigmoidf_(float x) { return 1.0f / (1.0f + __expf(-x)); }

__device__ __forceinline__ float bcef_(float p, float t) {
  float lp = __logf(fminf(fmaxf(p, EPS_C), 1.0f));
  float lq = __logf(fminf(fmaxf(1.0f - p, EPS_C), 1.0f));
  return -(t * lp + (1.0f - t) * lq);
}

// One block (64 threads) per batch; thread t handles target t.
__global__ void yolo_prep(const float* __restrict__ outp,
                          const float* __restrict__ target,
                          const float* __restrict__ anchors,
                          TRec* __restrict__ recs,
                          float4* __restrict__ boundsA,
                          float* __restrict__ areaA,
                          int* __restrict__ flatA,
                          int* __restrict__ clsA,
                          int* __restrict__ nvalid,
                          float* __restrict__ minarr)
{
  int b = blockIdx.x;
  int t = threadIdx.x;
  const float* tb = target + b * (MAXT * NLC) + t * NLC;
  float v1 = (t < MAXT) ? tb[1] : 0.0f;
  unsigned long long vm = __ballot(v1 > 0.0f);
  bool valid = false;
  float marea = 1e30f;
  if (t < MAXT) {
    // prefix-validity: all targets s<=t have tb[s][1] > 0
    valid = ((~vm) & ((2ULL << t) - 1ULL)) == 0ULL;

    float gx = tb[1] * (float)NW, gy = tb[2] * (float)NH;
    float gw = tb[10] * NET_WH,   gh = tb[11] * NET_WH;

    // best anchor (argmax anchor-overlap IOU, first-index wins ties)
    int bn = 0; float best = -1e30f;
    for (int k = 0; k < NANCH_PER; ++k) {
      float aw = anchors[2*k], ah = anchors[2*k+1];
      float inter = fminf(gw, aw) * fminf(gh, ah);
      float r = inter / (gw * gh + aw * ah - inter);
      if (r > best) { best = r; bn = k; }
    }
    float aw = anchors[2*bn], ah = anchors[2*bn+1];

    int gi = min(max((int)floorf(gx), 0), NW - 1);
    int gj = min(max((int)floorf(gy), 0), NH - 1);
    int pixq = gj * NW + gi;
    int flat = bn * NPIX + pixq;

    // gather pred box at assigned cell
    const float* cb = outp + ((size_t)(b * NANCH_PER + bn) * NCH) * NPIX + pixq;
    float px = sigmoidf_(cb[0]) + (float)gi;
    float py = sigmoidf_(cb[NPIX]) + (float)gj;
    float pw = __expf(cb[9 * NPIX]) * aw;
    float ph = __expf(cb[10 * NPIX]) * ah;

    float cw  = fminf(gx + 0.5f*gw, px + 0.5f*pw) - fmaxf(gx - 0.5f*gw, px - 0.5f*pw);
    float chh = fminf(gy + 0.5f*gh, py + 0.5f*ph) - fmaxf(gy - 0.5f*gh, py - 0.5f*ph);
    float inter = (cw > 0.0f && chh > 0.0f) ? cw * chh : 0.0f;
    float iou = inter / (gw * gh + pw * ph - inter);

    TRec r;
    r.x1 = gx - 0.5f * gw; r.x2 = gx + 0.5f * gw;
    r.y1 = gy - 0.5f * gh; r.y2 = gy + 0.5f * gh;
    r.area = gw * gh;
    r.flat = valid ? flat : -1;
    r.iou = iou;
    r.cls = (int)tb[0];
    r.vals[0] = gx - (float)gi;
    r.vals[1] = gy - (float)gj;
    #pragma unroll
    for (int k = 0; k < 7; ++k) r.vals[2 + k] = tb[3 + k];
    float sgw = valid ? gw : 1.0f, sgh = valid ? gh : 1.0f;
    r.vals[9]  = __logf(sgw / aw);
    r.vals[10] = __logf(sgh / ah);
    r.pad = 0.0f;
    recs[b * MAXT + t] = r;
    boundsA[b * MAXT + t] = make_float4(r.x1, r.x2, r.y1, r.y2);
    areaA[b * MAXT + t] = r.area;
    flatA[b * MAXT + t] = r.flat;
    clsA[b * MAXT + t]  = r.cls;
    if (valid) marea = gw * gh;
  }
  unsigned long long vm2 = __ballot(valid);
  #pragma unroll
  for (int off = 32; off > 0; off >>= 1) marea = fminf(marea, __shfl_xor(marea, off, 64));
  if (t == 0) { nvalid[b] = __popcll(vm2); minarr[b] = marea; }
}

__device__ __forceinline__ float elem4(const float4& v, int e) {
  return e == 0 ? v.x : (e == 1 ? v.y : (e == 2 ? v.z : v.w));
}

__global__ __launch_bounds__(256) void yolo_loss(
    const float* __restrict__ outp,
    const TRec* __restrict__ recs,
    const float4* __restrict__ boundsA,
    const float* __restrict__ areaA,
    const int* __restrict__ flatA,
    const int* __restrict__ clsA,
    const int* __restrict__ nvalid,
    const float* __restrict__ minarr,
    const float* __restrict__ anchors,
    float* __restrict__ partial)
{
  __shared__ float4 s_b4[MAXT];
  __shared__ float  s_area[MAXT];
  __shared__ int    s_flat[MAXT];
  __shared__ int    s_cls[MAXT];
  __shared__ int    s_nv;
  __shared__ float  s_minarea;
  __shared__ unsigned long long s_mask[2];
  __shared__ float  wsum[4];

  int blk = blockIdx.x;
  int b   = blk / (NANCH_PER * SUBB);
  int rem = blk % (NANCH_PER * SUBB);
  int a   = rem / SUBB;
  int sb  = rem % SUBB;
  int tid = threadIdx.x;
  int k0  = 2 * sb;

  if (tid < MAXT) {
    s_b4[tid]   = boundsA[b * MAXT + tid];
    s_area[tid] = areaA[b * MAXT + tid];
    s_flat[tid] = flatA[b * MAXT + tid];
    s_cls[tid]  = clsA[b * MAXT + tid];
  }
  if (tid == 0) { s_nv = nvalid[b]; s_minarea = minarr[b]; }
  __syncthreads();

  // per-chunk match masks (chunk = 1024 pixels); wave 0 only
  if (tid < 64) {
    int t = tid;
    bool in = (t < s_nv);
    int f = in ? s_flat[t] : -1;
    #pragma unroll
    for (int q = 0; q < 2; ++q) {
      int lo = a * NPIX + (k0 + q) * 1024;
      int hi = a * NPIX + min((k0 + q + 1) * 1024, NPIX);
      unsigned long long mm = __ballot(in && f >= lo && f < hi);
      if (t == 0) s_mask[q] = mm;
    }
  }
  __syncthreads();

  float aw = anchors[2*a], ah = anchors[2*a+1];
  // screen: 2*parea > minarea  <=>  tw+th > log(minarea / (2*aw*ah))
  float logthr = __logf(s_minarea / (2.0f * aw * ah));

  const float* plane = outp + ((size_t)(b * NANCH_PER + a) * NCH) * NPIX;
  const float4* tw4p = (const float4*)(plane + 9  * NPIX);
  const float4* th4p = (const float4*)(plane + 10 * NPIX);
  const float4* tc4p = (const float4*)(plane + 11 * NPIX);

  float local = 0.0f;
  #pragma unroll
  for (int q = 0; q < 2; ++q) {
    int g = (k0 + q) * 256 + tid;
    if (g < NG4) {
      float4 tw4 = tw4p[g];
      float4 th4 = th4p[g];
      float4 tc4 = tc4p[g];
      unsigned long long mm0 = s_mask[q];
      #pragma unroll
      for (int e = 0; e < 4; ++e) {
        float tw = elem4(tw4, e), th = elem4(th4, e), tc = elem4(tc4, e);
        int pix = 4 * g + e;
        int myflat = a * NPIX + pix;

        int match = -1;
        unsigned cmask = 0;
        unsigned long long mm = mm0;
        while (mm) {
          int t = (int)__builtin_ctzll(mm); mm &= mm - 1;
          if (s_flat[t] == myflat) { match = t; cmask |= (1u << s_cls[t]); }
        }

        bool over = false;
        if (match < 0 && tw + th > logthr) {
          int j = pix / NW;
          int i = pix - j * NW;
          float sx = sigmoidf_(plane[pix]), sy = sigmoidf_(plane[NPIX + pix]);
          float pw = __expf(tw) * aw, ph = __expf(th) * ah;
          float parea = pw * ph;
          float px = sx + (float)i, py = sy + (float)j;
          float pxl = px - 0.5f * pw, pxh = px + 0.5f * pw;
          float pyl = py - 0.5f * ph, pyh = py + 0.5f * ph;
          int nv = s_nv;
          for (int t = 0; t < nv; ++t) {
            float4 bb = s_b4[t];
            float cw  = fminf(pxh, bb.y) - fmaxf(pxl, bb.x);
            float chh = fminf(pyh, bb.w) - fmaxf(pyl, bb.z);
            float inter = (cw > 0.0f && chh > 0.0f) ? cw * chh : 0.0f;
            over = over || (3.0f * inter > parea + s_area[t]);
          }
        }

        if (match >= 0) {
          int j = pix / NW;
          int i = pix - j * NW;
          float sx = sigmoidf_(plane[pix]), sy = sigmoidf_(plane[NPIX + pix]);
          float conf = sigmoidf_(tc);
          TRec r = recs[b * MAXT + match];
          local += bcef_(conf, r.iou);
          local += bcef_(sx, r.vals[0]) + bcef_(sy, r.vals[1]);
          float d9 = tw - r.vals[9], d10 = th - r.vals[10];
          local += d9 * d9 + d10 * d10;
          float c2 = plane[2*NPIX+pix], c3 = plane[3*NPIX+pix], c4 = plane[4*NPIX+pix];
          float e2 = c2 - r.vals[2], e3 = c3 - r.vals[3], e4 = c4 - r.vals[4];
          float ss = e2*e2 + e3*e3 + e4*e4;
          float dis = sqrtf(ss);
          if (dis <= BETA_C) local += 0.5f * ss / BETA_C;
          else local += fabsf(e2) + fabsf(e3) + fabsf(e4) - 0.5f * BETA_C;
          float c5 = plane[5*NPIX+pix], c6 = plane[6*NPIX+pix];
          float c7 = plane[7*NPIX+pix], c8 = plane[8*NPIX+pix];
          float rn = fmaxf(sqrtf(c5*c5 + c6*c6 + c7*c7 + c8*c8), 1e-12f);
          local += fabsf(c5/rn - r.vals[5]) + fabsf(c6/rn - r.vals[6])
                 + fabsf(c7/rn - r.vals[7]) + fabsf(c8/rn - r.vals[8]);
          #pragma unroll
          for (int c = 0; c < NCLS; ++c) {
            float x = plane[(NLC + c) * NPIX + pix];
            float tt = ((cmask >> c) & 1u) ? 1.0f : 0.0f;
            local += fmaxf(x, 0.0f) - x * tt + __logf(1.0f + __expf(-fabsf(x)));
          }
        } else if (!over) {
          // noobj: bce(sigmoid(tc), 0) = min(softplus(tc), -log(EPS))
          local += fminf(__logf(1.0f + __expf(tc)), LOGEPS);
        }
      }
    }
  }

  #pragma unroll
  for (int off = 32; off > 0; off >>= 1) local += __shfl_down(local, off, 64);
  if ((tid & 63) == 0) wsum[tid >> 6] = local;
  __syncthreads();
  if (tid == 0) partial[blk] = wsum[0] + wsum[1] + wsum[2] + wsum[3];
}

__global__ __launch_bounds__(256) void yolo_final(const float* __restrict__ partial,
                                                  float* __restrict__ out)
{
  __shared__ float w[4];
  float s = 0.0f;
  for (int i = threadIdx.x; i < NBLK; i += 256) s += partial[i];
  #pragma unroll
  for (int off = 32; off > 0; off >>= 1) s += __shfl_down(s, off, 64);
  if ((threadIdx.x & 63) == 0) w[threadIdx.x >> 6] = s;
  __syncthreads();
  if (threadIdx.x == 0) out[0] = (w[0] + w[1] + w[2] + w[3]) * (1.0f / (float)NBATCH);
}

extern "C" void kernel_launch(void* const* d_in, const int* in_sizes, int n_in,
                              void* d_out, int out_size, void* d_ws, size_t ws_size,
                              hipStream_t stream) {
  const float* outp    = (const float*)d_in[0];
  const float* target  = (const float*)d_in[1];
  const float* anchors = (const float*)d_in[2];

  char* ws = (char*)d_ws;
  size_t off = 0;
  TRec*   recs    = (TRec*)  (ws + off); off += (size_t)NBATCH * MAXT * sizeof(TRec);   // 256000
  float4* boundsA = (float4*)(ws + off); off += (size_t)NBATCH * MAXT * sizeof(float4); // 51200
  float*  areaA   = (float*) (ws + off); off += (size_t)NBATCH * MAXT * sizeof(float);
  int*    flatA   = (int*)   (ws + off); off += (size_t)NBATCH * MAXT * sizeof(int);
  int*    clsA    = (int*)   (ws + off); off += (size_t)NBATCH * MAXT * sizeof(int);
  int*    nv      = (int*)   (ws + off); off += 256;
  float*  minarr  = (float*) (ws + off); off += 256;
  float*  partial = (float*) (ws + off);

  yolo_prep<<<NBATCH, 64, 0, stream>>>(outp, target, anchors, recs, boundsA, areaA,
                                       flatA, clsA, nv, minarr);
  yolo_loss<<<NBLK, 256, 0, stream>>>(outp, recs, boundsA, areaA, flatA, clsA,
                                      nv, minarr, anchors, partial);
  yolo_final<<<1, 256, 0, stream>>>(partial, (float*)d_out);
}

// Round 4
// 158.198 us; speedup vs baseline: 1.0562x; 1.0562x over previous
//
#include <hip/hip_runtime.h>
#include <math.h>

#define NBATCH 64
#define NANCH_PER 3
#define NCLS 13
#define NH 76
#define NW 76
#define NPIX (NH*NW)             // 5776
#define NG4 (NPIX/4)             // 1444 float4 groups per plane (exact)
#define MAXT 50
#define NLC 12
#define NCH (NLC + NCLS)         // 25 channels
#define BETA_C 0.028f
#define EPS_C 1e-12f
#define NET_WH 608.0f
#define SUBB 6                   // sub-blocks per (b,a); each covers 256 float4 groups (1024 px)
#define NBLK (NBATCH*NANCH_PER*SUBB)  // 1152
#define LOGEPS 27.6310211159285f // -log(1e-12)

struct TRec {
  float x1, x2, y1, y2;
  float area;
  int   flat;                   // within-batch flat index (a*NPIX + pix), -1 if invalid
  float iou;                    // iou_t
  int   cls;
  float vals[11];               // tcoord values
  float pad;
};  // 80 B

__device__ __forceinline__ float sigmoidf_(float x) { return 1.0f / (1.0f + __expf(-x)); }

__device__ __forceinline__ float bcef_(float p, float t) {
  float lp = __logf(fminf(fmaxf(p, EPS_C), 1.0f));
  float lq = __logf(fminf(fmaxf(1.0f - p, EPS_C), 1.0f));
  return -(t * lp + (1.0f - t) * lq);
}

// One block (64 threads) per batch; thread t handles target t.
__global__ void yolo_prep(const float* __restrict__ outp,
                          const float* __restrict__ target,
                          const float* __restrict__ anchors,
                          TRec* __restrict__ recs,
                          float4* __restrict__ boundsA,
                          float* __restrict__ areaA,
                          int* __restrict__ flatA,
                          int* __restrict__ clsA,
                          int* __restrict__ nvalid,
                          float* __restrict__ minarr)
{
  int b = blockIdx.x;
  int t = threadIdx.x;
  const float* tb = target + b * (MAXT * NLC) + t * NLC;
  float v1 = (t < MAXT) ? tb[1] : 0.0f;
  unsigned long long vm = __ballot(v1 > 0.0f);
  bool valid = false;
  float marea = 1e30f;
  if (t < MAXT) {
    // prefix-validity: all targets s<=t have tb[s][1] > 0
    valid = ((~vm) & ((2ULL << t) - 1ULL)) == 0ULL;

    float gx = tb[1] * (float)NW, gy = tb[2] * (float)NH;
    float gw = tb[10] * NET_WH,   gh = tb[11] * NET_WH;

    // best anchor (argmax anchor-overlap IOU, first-index wins ties)
    int bn = 0; float best = -1e30f;
    for (int k = 0; k < NANCH_PER; ++k) {
      float aw = anchors[2*k], ah = anchors[2*k+1];
      float inter = fminf(gw, aw) * fminf(gh, ah);
      float r = inter / (gw * gh + aw * ah - inter);
      if (r > best) { best = r; bn = k; }
    }
    float aw = anchors[2*bn], ah = anchors[2*bn+1];

    int gi = min(max((int)floorf(gx), 0), NW - 1);
    int gj = min(max((int)floorf(gy), 0), NH - 1);
    int pixq = gj * NW + gi;
    int flat = bn * NPIX + pixq;

    // gather pred box at assigned cell
    const float* cb = outp + ((size_t)(b * NANCH_PER + bn) * NCH) * NPIX + pixq;
    float px = sigmoidf_(cb[0]) + (float)gi;
    float py = sigmoidf_(cb[NPIX]) + (float)gj;
    float pw = __expf(cb[9 * NPIX]) * aw;
    float ph = __expf(cb[10 * NPIX]) * ah;

    float cw  = fminf(gx + 0.5f*gw, px + 0.5f*pw) - fmaxf(gx - 0.5f*gw, px - 0.5f*pw);
    float chh = fminf(gy + 0.5f*gh, py + 0.5f*ph) - fmaxf(gy - 0.5f*gh, py - 0.5f*ph);
    float inter = (cw > 0.0f && chh > 0.0f) ? cw * chh : 0.0f;
    float iou = inter / (gw * gh + pw * ph - inter);

    TRec r;
    r.x1 = gx - 0.5f * gw; r.x2 = gx + 0.5f * gw;
    r.y1 = gy - 0.5f * gh; r.y2 = gy + 0.5f * gh;
    r.area = gw * gh;
    r.flat = valid ? flat : -1;
    r.iou = iou;
    r.cls = (int)tb[0];
    r.vals[0] = gx - (float)gi;
    r.vals[1] = gy - (float)gj;
    #pragma unroll
    for (int k = 0; k < 7; ++k) r.vals[2 + k] = tb[3 + k];
    float sgw = valid ? gw : 1.0f, sgh = valid ? gh : 1.0f;
    r.vals[9]  = __logf(sgw / aw);
    r.vals[10] = __logf(sgh / ah);
    r.pad = 0.0f;
    recs[b * MAXT + t] = r;
    boundsA[b * MAXT + t] = make_float4(r.x1, r.x2, r.y1, r.y2);
    areaA[b * MAXT + t] = r.area;
    flatA[b * MAXT + t] = r.flat;
    clsA[b * MAXT + t]  = r.cls;
    if (valid) marea = gw * gh;
  }
  unsigned long long vm2 = __ballot(valid);
  #pragma unroll
  for (int off = 32; off > 0; off >>= 1) marea = fminf(marea, __shfl_xor(marea, off, 64));
  if (t == 0) { nvalid[b] = __popcll(vm2); minarr[b] = marea; }
}

__device__ __forceinline__ float elem4(const float4& v, int e) {
  return e == 0 ? v.x : (e == 1 ? v.y : (e == 2 ? v.z : v.w));
}

__global__ __launch_bounds__(256) void yolo_loss(
    const float* __restrict__ outp,
    const TRec* __restrict__ recs,
    const float4* __restrict__ boundsA,
    const float* __restrict__ areaA,
    const int* __restrict__ flatA,
    const int* __restrict__ clsA,
    const int* __restrict__ nvalid,
    const float* __restrict__ minarr,
    const float* __restrict__ anchors,
    float* __restrict__ partial)
{
  __shared__ float4 s_b4[MAXT];
  __shared__ float  s_area[MAXT];
  __shared__ int    s_flat[MAXT];
  __shared__ int    s_cls[MAXT];
  __shared__ int    s_nv;
  __shared__ float  s_minarea;
  __shared__ unsigned long long s_mask;
  __shared__ float  wsum[4];

  int blk = blockIdx.x;
  int b   = blk / (NANCH_PER * SUBB);
  int rem = blk % (NANCH_PER * SUBB);
  int a   = rem / SUBB;
  int sb  = rem % SUBB;
  int tid = threadIdx.x;

  if (tid < MAXT) {
    s_b4[tid]   = boundsA[b * MAXT + tid];
    s_area[tid] = areaA[b * MAXT + tid];
    s_flat[tid] = flatA[b * MAXT + tid];
    s_cls[tid]  = clsA[b * MAXT + tid];
  }
  if (tid == 0) { s_nv = nvalid[b]; s_minarea = minarr[b]; }
  __syncthreads();

  // block-range match mask (block covers 1024 consecutive pixels); wave 0 only
  if (tid < 64) {
    int t = tid;
    bool in = (t < s_nv);
    int f = in ? s_flat[t] : -1;
    int lo = a * NPIX + sb * 1024;
    int hi = a * NPIX + min((sb + 1) * 1024, NPIX);
    unsigned long long mm = __ballot(in && f >= lo && f < hi);
    if (t == 0) s_mask = mm;
  }
  __syncthreads();

  float aw = anchors[2*a], ah = anchors[2*a+1];
  // screen: 2*parea > minarea  <=>  tw+th > log(minarea / (2*aw*ah))
  float logthr = __logf(s_minarea / (2.0f * aw * ah));

  const float* plane = outp + ((size_t)(b * NANCH_PER + a) * NCH) * NPIX;
  const float4* tw4p = (const float4*)(plane + 9  * NPIX);
  const float4* th4p = (const float4*)(plane + 10 * NPIX);
  const float4* tc4p = (const float4*)(plane + 11 * NPIX);

  float local = 0.0f;
  int g = sb * 256 + tid;
  if (g < NG4) {
    float4 tw4 = tw4p[g];
    float4 th4 = th4p[g];
    float4 tc4 = tc4p[g];
    unsigned long long mm0 = s_mask;
    #pragma unroll
    for (int e = 0; e < 4; ++e) {
      float tw = elem4(tw4, e), th = elem4(th4, e), tc = elem4(tc4, e);
      int pix = 4 * g + e;
      int myflat = a * NPIX + pix;

      int match = -1;
      unsigned cmask = 0;
      unsigned long long mm = mm0;
      while (mm) {
        int t = (int)__builtin_ctzll(mm); mm &= mm - 1;
        if (s_flat[t] == myflat) { match = t; cmask |= (1u << s_cls[t]); }
      }

      bool over = false;
      if (match < 0 && tw + th > logthr) {
        int j = pix / NW;
        int i = pix - j * NW;
        float sx = sigmoidf_(plane[pix]), sy = sigmoidf_(plane[NPIX + pix]);
        float pw = __expf(tw) * aw, ph = __expf(th) * ah;
        float parea = pw * ph;
        float px = sx + (float)i, py = sy + (float)j;
        float pxl = px - 0.5f * pw, pxh = px + 0.5f * pw;
        float pyl = py - 0.5f * ph, pyh = py + 0.5f * ph;
        int nv = s_nv;
        for (int t = 0; t < nv; ++t) {
          float4 bb = s_b4[t];
          float cw  = fminf(pxh, bb.y) - fmaxf(pxl, bb.x);
          float chh = fminf(pyh, bb.w) - fmaxf(pyl, bb.z);
          float inter = (cw > 0.0f && chh > 0.0f) ? cw * chh : 0.0f;
          over = over || (3.0f * inter > parea + s_area[t]);
        }
      }

      if (match >= 0) {
        int j = pix / NW;
        int i = pix - j * NW;
        float sx = sigmoidf_(plane[pix]), sy = sigmoidf_(plane[NPIX + pix]);
        float conf = sigmoidf_(tc);
        TRec r = recs[b * MAXT + match];
        local += bcef_(conf, r.iou);
        local += bcef_(sx, r.vals[0]) + bcef_(sy, r.vals[1]);
        float d9 = tw - r.vals[9], d10 = th - r.vals[10];
        local += d9 * d9 + d10 * d10;
        float c2 = plane[2*NPIX+pix], c3 = plane[3*NPIX+pix], c4 = plane[4*NPIX+pix];
        float e2 = c2 - r.vals[2], e3 = c3 - r.vals[3], e4 = c4 - r.vals[4];
        float ss = e2*e2 + e3*e3 + e4*e4;
        float dis = sqrtf(ss);
        if (dis <= BETA_C) local += 0.5f * ss / BETA_C;
        else local += fabsf(e2) + fabsf(e3) + fabsf(e4) - 0.5f * BETA_C;
        float c5 = plane[5*NPIX+pix], c6 = plane[6*NPIX+pix];
        float c7 = plane[7*NPIX+pix], c8 = plane[8*NPIX+pix];
        float rn = fmaxf(sqrtf(c5*c5 + c6*c6 + c7*c7 + c8*c8), 1e-12f);
        local += fabsf(c5/rn - r.vals[5]) + fabsf(c6/rn - r.vals[6])
               + fabsf(c7/rn - r.vals[7]) + fabsf(c8/rn - r.vals[8]);
        #pragma unroll
        for (int c = 0; c < NCLS; ++c) {
          float x = plane[(NLC + c) * NPIX + pix];
          float tt = ((cmask >> c) & 1u) ? 1.0f : 0.0f;
          local += fmaxf(x, 0.0f) - x * tt + __logf(1.0f + __expf(-fabsf(x)));
        }
      } else if (!over) {
        // noobj: bce(sigmoid(tc), 0) = min(softplus(tc), -log(EPS))
        local += fminf(__logf(1.0f + __expf(tc)), LOGEPS);
      }
    }
  }

  #pragma unroll
  for (int off = 32; off > 0; off >>= 1) local += __shfl_down(local, off, 64);
  if ((tid & 63) == 0) wsum[tid >> 6] = local;
  __syncthreads();
  if (tid == 0) partial[blk] = wsum[0] + wsum[1] + wsum[2] + wsum[3];
}

__global__ __launch_bounds__(256) void yolo_final(const float* __restrict__ partial,
                                                  float* __restrict__ out)
{
  __shared__ float w[4];
  float s = 0.0f;
  for (int i = threadIdx.x; i < NBLK; i += 256) s += partial[i];
  #pragma unroll
  for (int off = 32; off > 0; off >>= 1) s += __shfl_down(s, off, 64);
  if ((threadIdx.x & 63) == 0) w[threadIdx.x >> 6] = s;
  __syncthreads();
  if (threadIdx.x == 0) out[0] = (w[0] + w[1] + w[2] + w[3]) * (1.0f / (float)NBATCH);
}

extern "C" void kernel_launch(void* const* d_in, const int* in_sizes, int n_in,
                              void* d_out, int out_size, void* d_ws, size_t ws_size,
                              hipStream_t stream) {
  const float* outp    = (const float*)d_in[0];
  const float* target  = (const float*)d_in[1];
  const float* anchors = (const float*)d_in[2];

  char* ws = (char*)d_ws;
  size_t off = 0;
  TRec*   recs    = (TRec*)  (ws + off); off += (size_t)NBATCH * MAXT * sizeof(TRec);   // 256000
  float4* boundsA = (float4*)(ws + off); off += (size_t)NBATCH * MAXT * sizeof(float4); // 51200
  float*  areaA   = (float*) (ws + off); off += (size_t)NBATCH * MAXT * sizeof(float);
  int*    flatA   = (int*)   (ws + off); off += (size_t)NBATCH * MAXT * sizeof(int);
  int*    clsA    = (int*)   (ws + off); off += (size_t)NBATCH * MAXT * sizeof(int);
  int*    nv      = (int*)   (ws + off); off += 256;
  float*  minarr  = (float*) (ws + off); off += 256;
  float*  partial = (float*) (ws + off);

  yolo_prep<<<NBATCH, 64, 0, stream>>>(outp, target, anchors, recs, boundsA, areaA,
                                       flatA, clsA, nv, minarr);
  yolo_loss<<<NBLK, 256, 0, stream>>>(outp, recs, boundsA, areaA, flatA, clsA,
                                      nv, minarr, anchors, partial);
  yolo_final<<<1, 256, 0, stream>>>(partial, (float*)d_out);
}